// Round 17
// baseline (4153.231 us; speedup 1.0000x reference)
//
#include <hip/hip_runtime.h>
#include <stdint.h>

typedef _Float16 f16;
typedef _Float16 f16x8 __attribute__((ext_vector_type(8)));
typedef float f32x4 __attribute__((ext_vector_type(4)));
typedef uint32_t u32;

#define SEQ 8192
#define NH 16
#define HDIM 128
#define BHCNT 32
#define KDIM 2048
#define SCALE 0.08838834764831845f
#define LOGW 3.4657359027997265f
#define TAU1 0.06f
#define TAU 6e-3f
#define MAXWL 32768
#define BCAP 1024
#define BCAP3 512

__device__ __forceinline__ f32x4 mfma16(f16x8 a, f16x8 b, f32x4 c){
  return __builtin_amdgcn_mfma_f32_16x16x32_f16(a, b, c, 0, 0, 0);
}

__device__ __forceinline__ void g2l16(const f16* g, f16* l){
  __builtin_amdgcn_global_load_lds(
      (const __attribute__((address_space(1))) void*)g,
      (__attribute__((address_space(3))) void*)l, 16, 0, 0);
}

// ---------- prep: x -> f16 ----------
__global__ __launch_bounds__(256) void split_x_k(const float* __restrict__ x,
                                                 f16* __restrict__ xh){
  size_t i = ((size_t)blockIdx.x * 256 + threadIdx.x) * 4;
  float4 v = *(const float4*)(x + i);
  union { f16 h[4]; ushort4 u; } a;
  a.h[0]=(f16)v.x; a.h[1]=(f16)v.y; a.h[2]=(f16)v.z; a.h[3]=(f16)v.w;
  *(ushort4*)(xh + i) = a.u;
}

// ---------- prep: transpose+convert weights (in [Kd][Nd] -> out [Nd][Kd]) ----------
__global__ void transpose_k(const float* __restrict__ in, f16* __restrict__ ohi,
                            f16* __restrict__ olo, int Kd, int Nd, int NLO){
  __shared__ float t[32][33];
  int tx = threadIdx.x, ty = threadIdx.y;
  int n0 = blockIdx.x*32, k0 = blockIdx.y*32;
  #pragma unroll
  for (int i=0;i<4;i++) t[ty+i*8][tx] = in[(size_t)(k0+ty+i*8)*Nd + n0+tx];
  __syncthreads();
  #pragma unroll
  for (int i=0;i<4;i++){
    int n = n0 + ty + i*8, k = k0 + tx;
    float v = t[tx][ty+i*8];
    f16 h = (f16)v;
    ohi[(size_t)n*Kd + k] = h;
    if (n < NLO) olo[(size_t)n*Kd + k] = (f16)(v - (float)h);
  }
}

// ---------- prep: rope cos/sin table (numpy-exact inv_freq double rounding) ----------
__global__ __launch_bounds__(256) void rope_table_k(float* __restrict__ ct, float* __restrict__ st){
  int i = blockIdx.x * 256 + threadIdx.x;
  int s = i >> 6, d = i & 63;
  float p32 = (float)pow(10000.0, (double)d / 64.0);
  float inv = __fdiv_rn(1.0f, p32);
  float f = __fmul_rn((float)s, inv);
  double a = (double)f;
  ct[i] = (float)cos(a);
  st[i] = (float)sin(a);
}

__global__ void zero_k(int* p){ p[0] = 0; p[1] = 0; p[2] = 0; }

// ---------- diagnostic: only fires if flagging machinery is broken ----------
__global__ void diag_k(const int* __restrict__ flags, float* __restrict__ out){
  int c = flags[0];
  if (c == 0 || c >= MAXWL || flags[2]) out[0] = 1.0e9f + (float)c;
}

// ---------- GEMM: A[M][K] * Bt[N][K]^T, XCD strip + L2-blocked bcol groups ----------
template<int MODE, int NC, int GS>
__global__ __launch_bounds__(256) void gemm_k(
    const f16* __restrict__ A, const f16* __restrict__ Bt,
    f16* __restrict__ q16, f16* __restrict__ k16, f16* __restrict__ v16,
    float* __restrict__ o0, int N){
  __shared__ f16 sm[8192];
  const int tid = threadIdx.x, lane = tid & 63, wave = tid >> 6;
  const int wr = wave >> 1, wc = wave & 1;
  const int wg = blockIdx.x;
  const int xcd = wg & 7, wgl = wg >> 3;
  const int grp = wgl / (16*GS);
  const int rem = wgl % (16*GS);
  const int brow = xcd*16 + rem / GS;
  const int bcol = grp*GS + rem % GS;
  const int g = lane >> 4, q_ = lane & 15;
  f32x4 acc[4][4];
  #pragma unroll
  for (int m=0;m<4;m++)
    #pragma unroll
    for (int n=0;n<4;n++) acc[m][n] = (f32x4){0.f,0.f,0.f,0.f};
  const int srow = tid >> 2, sseg = tid & 3;
  const int scol = (sseg ^ (srow & 3)) * 8;
  const f16* ga0 = A  + (size_t)(brow*128 + srow)*KDIM + scol;
  const f16* gb0 = Bt + (size_t)(bcol*128 + srow)*KDIM + scol;
  f16* As = sm; f16* Bs = sm + 4096;
  f16* dA0 = As + wave*512; f16* dA1 = As + 2048 + wave*512;
  f16* dB0 = Bs + wave*512; f16* dB1 = Bs + 2048 + wave*512;
  const int aoff = (wr*64 + q_)*32 + (g ^ (q_ & 3))*8;
  const int boff = (wc*64 + q_)*32 + (g ^ (q_ & 3))*8;
  for (int kt = 0; kt < KDIM/32; ++kt){
    const size_t ko = (size_t)kt * 32;
    g2l16(ga0 + ko, dA0); g2l16(ga0 + (size_t)64*KDIM + ko, dA1);
    g2l16(gb0 + ko, dB0); g2l16(gb0 + (size_t)64*KDIM + ko, dB1);
    __syncthreads();
    f16x8 af[4];
    #pragma unroll
    for (int m=0;m<4;m++) af[m] = *(const f16x8*)&As[aoff + m*16*32];
    #pragma unroll
    for (int n=0;n<4;n++){
      f16x8 bf = *(const f16x8*)&Bs[boff + n*16*32];
      #pragma unroll
      for (int m=0;m<4;m++) acc[m][n] = mfma16(af[m], bf, acc[m][n]);
    }
    __syncthreads();
  }
  #pragma unroll
  for (int m=0;m<4;m++)
    #pragma unroll
    for (int n=0;n<4;n++)
      #pragma unroll
      for (int j=0;j<4;j++){
        int row = brow*128 + wr*64 + m*16 + g*4 + j;
        int col = bcol*128 + wc*64 + n*16 + q_;
        float v = acc[m][n][j];
        if constexpr (MODE == 0){
          o0[(size_t)row * N + col] = v;
        } else {
          int b = row >> 13, s = row & 8191;
          int sec = col >> 11;                 // 0=q, 1=k, 2=v
          int cl = col & 2047;
          int h = cl >> 7, hd = cl & 127;
          f16* dst = (sec == 0) ? q16 : ((sec == 1) ? k16 : v16);
          dst[(((size_t)b*NH + h)*SEQ + s)*HDIM + hd] = (f16)v;
        }
      }
}

// ---------- rope (f32 math, f16 in/out in place) + LSH hash + TAU1 flagging ----------
__global__ __launch_bounds__(256) void rope_hash_k(f16* __restrict__ qk, const float* __restrict__ ct,
    const float* __restrict__ st, const float* __restrict__ proj, int* __restrict__ hout,
    int tag, int* __restrict__ wl, int* __restrict__ wcnt){
  const int lane = threadIdx.x & 63, wave = threadIdx.x >> 6;
  const int s = blockIdx.x * 4 + wave, bh = blockIdx.y;
  f16* row = qk + ((size_t)bh * SEQ + s) * HDIM;
  float vx = (float)row[2*lane], vy = (float)row[2*lane+1];
  float ox = __shfl_xor(vx, 32), oy = __shfl_xor(vy, 32);
  const int dl = 2*lane, di = dl & 63;
  const float* cb = ct + (size_t)s*64; const float* sb = st + (size_t)s*64;
  float c0 = cb[di], c1 = cb[di+1], sn0 = sb[di], sn1 = sb[di+1];
  float r0, r1;
  if (lane < 32){ r0 = vx*c0 - ox*sn0; r1 = vy*c1 - oy*sn1; }
  else          { r0 = vx*c0 + ox*sn0; r1 = vy*c1 + oy*sn1; }
  union { f16 h[2]; u32 u; } pk;
  pk.h[0] = (f16)r0; pk.h[1] = (f16)r1;
  *(u32*)(row + dl) = pk.u;
  float part[7];
  #pragma unroll
  for (int p=0;p<7;p++) part[p] = r0*proj[dl*7+p] + r1*proj[(dl+1)*7+p];
  #pragma unroll
  for (int off=32; off>=1; off>>=1){
    #pragma unroll
    for (int p=0;p<7;p++) part[p] += __shfl_xor(part[p], off);
  }
  if (lane == 0){
    int hs = 0; float mn = 1e30f;
    #pragma unroll
    for (int p=0;p<7;p++){ if (part[p] > 0.f) hs |= (1<<p); mn = fminf(mn, fabsf(part[p])); }
    hout[bh*SEQ + s] = hs;
    if (mn < TAU1){
      int w = atomicAdd(wcnt, 1);
      if (w < MAXWL){ wl[2*w] = (bh<<1) | tag; wl[2*w+1] = s; }
    }
  }
}

// ---------- bucket flagged rows by (tag, head); CAP-templated ----------
template<int CAP>
__global__ __launch_bounds__(256) void bucket_k(const int* __restrict__ wl, const int* __restrict__ wcnt,
    int* __restrict__ wl2, int* __restrict__ cnt2, int* __restrict__ flags){
  const int bucket = blockIdx.x;
  __shared__ int lcnt;
  if (threadIdx.x == 0) lcnt = 0;
  __syncthreads();
  int count = wcnt[0]; if (count > MAXWL) count = MAXWL;
  for (int i = threadIdx.x; i < count; i += 256){
    int tagbh = wl[2*i];
    int tag = tagbh & 1, h = (tagbh >> 1) & 15;
    if (tag*16 + h == bucket){
      int pos = atomicAdd(&lcnt, 1);
      if (pos < CAP) wl2[bucket*CAP + pos] = (tagbh << 13) | wl[2*i+1];
    }
  }
  __syncthreads();
  if (threadIdx.x == 0){
    cnt2[bucket] = (lcnt > CAP) ? CAP : lcnt;
    if (lcnt > CAP) atomicExch(&flags[2], 1);
  }
}

// ---------- tier-2b (FUSED): gathered split-grade GEMM + rope + rehash, 64-row batches ----------
__global__ __launch_bounds__(256) void t2_k(const float* __restrict__ x,
    const f16* __restrict__ wh, const f16* __restrict__ wlo,
    const int* __restrict__ wl2, const int* __restrict__ cnt2,
    const float* __restrict__ ct, const float* __restrict__ st, const float* __restrict__ proj,
    int* __restrict__ hq, int* __restrict__ hk, int* __restrict__ wl3, int* __restrict__ wcnt3){
  const int bucket = blockIdx.y;
  const int nrows = cnt2[bucket];
  const int base = blockIdx.x * 64;
  if (base >= nrows) return;
  const int tid = threadIdx.x, lane = tid & 63, wave = tid >> 6;
  const int g = lane >> 4, q_ = lane & 15;
  __shared__ f16 Ah[64*32], Alo[64*32], Bh[128*32], Bl[128*32];
  __shared__ float S[64][128];
  __shared__ int rs[64], ent[64];
  if (tid < 64){
    int idx = base + tid;
    int e = wl2[bucket*BCAP + (idx < nrows ? idx : 0)];
    ent[tid] = e;
    int s = e & 8191;
    int b = e >> 18;
    rs[tid] = b * SEQ + s;
  }
  __syncthreads();
  const int tag = bucket >> 4, h = bucket & 15;
  const f16* Wh = wh  + ((size_t)(tag*2048 + h*128)) * KDIM;
  const f16* Wl = wlo + ((size_t)(tag*2048 + h*128)) * KDIM;
  f32x4 acc[8];
  #pragma unroll
  for (int n=0;n<8;n++) acc[n] = (f32x4){0.f,0.f,0.f,0.f};
  const int arow = tid >> 2, aseg = tid & 3;
  const int bcol = tid >> 1, bhalf = tid & 1;
  const size_t abase = (size_t)rs[arow]*KDIM + aseg*8;
  const size_t bbase = (size_t)bcol*KDIM + bhalf*16;
  for (int kt = 0; kt < 64; ++kt){
    const int k0 = kt*32;
    {
      union { float4 f4[2]; float f[8]; } xa;
      xa.f4[0] = *(const float4*)(x + abase + k0);
      xa.f4[1] = *(const float4*)(x + abase + k0 + 4);
      union { f16 h[8]; f16x8 v; } hh, ll;
      #pragma unroll
      for (int i=0;i<8;i++){
        f16 hv = (f16)xa.f[i];
        hh.h[i] = hv;
        ll.h[i] = (f16)(xa.f[i] - (float)hv);
      }
      *(f16x8*)&Ah [arow*32 + aseg*8] = hh.v;
      *(f16x8*)&Alo[arow*32 + aseg*8] = ll.v;
    }
    *(f16x8*)&Bh[bcol*32 + bhalf*16]     = *(const f16x8*)(Wh + bbase + k0);
    *(f16x8*)&Bh[bcol*32 + bhalf*16 + 8] = *(const f16x8*)(Wh + bbase + k0 + 8);
    *(f16x8*)&Bl[bcol*32 + bhalf*16]     = *(const f16x8*)(Wl + bbase + k0);
    *(f16x8*)&Bl[bcol*32 + bhalf*16 + 8] = *(const f16x8*)(Wl + bbase + k0 + 8);
    __syncthreads();
    f16x8 ah = *(const f16x8*)&Ah [(wave*16 + q_)*32 + g*8];
    f16x8 al = *(const f16x8*)&Alo[(wave*16 + q_)*32 + g*8];
    #pragma unroll
    for (int n=0;n<8;n++){
      f16x8 bh8 = *(const f16x8*)&Bh[(n*16 + q_)*32 + g*8];
      f16x8 bl8 = *(const f16x8*)&Bl[(n*16 + q_)*32 + g*8];
      acc[n] = mfma16(ah, bh8, acc[n]);
      acc[n] = mfma16(ah, bl8, acc[n]);
      acc[n] = mfma16(al, bh8, acc[n]);
    }
    __syncthreads();
  }
  #pragma unroll
  for (int n=0;n<8;n++)
    #pragma unroll
    for (int j=0;j<4;j++)
      S[wave*16 + g*4 + j][n*16 + q_] = acc[n][j];
  __syncthreads();
  for (int r = 0; r < 16; ++r){
    int row = wave*16 + r;
    int gidx = base + row;
    if (gidx >= nrows) break;
    int e = ent[row];
    int s = e & 8191;
    int tagbh = e >> 13;
    int bh = tagbh >> 1;
    float vx = S[row][2*lane], vy = S[row][2*lane+1];
    float ox = __shfl_xor(vx, 32), oy = __shfl_xor(vy, 32);
    const int dl = 2*lane, di = dl & 63;
    float c0 = ct[(size_t)s*64 + di], c1v = ct[(size_t)s*64 + di + 1];
    float sn0 = st[(size_t)s*64 + di], sn1 = st[(size_t)s*64 + di + 1];
    float r0, r1;
    if (lane < 32){ r0 = vx*c0 - ox*sn0; r1 = vy*c1v - oy*sn1; }
    else          { r0 = vx*c0 + ox*sn0; r1 = vy*c1v + oy*sn1; }
    float part[7];
    #pragma unroll
    for (int p=0;p<7;p++) part[p] = r0*proj[dl*7+p] + r1*proj[(dl+1)*7+p];
    #pragma unroll
    for (int off=32; off>=1; off>>=1){
      #pragma unroll
      for (int p=0;p<7;p++) part[p] += __shfl_xor(part[p], off);
    }
    if (lane == 0){
      int hs = 0; float mn = 1e30f;
      #pragma unroll
      for (int p=0;p<7;p++){ if (part[p] > 0.f) hs |= (1<<p); mn = fminf(mn, fabsf(part[p])); }
      ((tagbh & 1) ? hk : hq)[bh*SEQ + s] = hs;
      if (mn < TAU){
        int w = atomicAdd(wcnt3, 1);
        if (w < MAXWL){ wl3[2*w] = tagbh; wl3[2*w+1] = s; }
      }
    }
  }
}

// ---------- tier-3: exact-f64 GEMM hash recompute, BUCKETED (L2 slab reuse) ----------
// One block per (tag,head) bucket; 4 waves stride the bucket's rows. All rows of a
// bucket read the SAME 1MB w_in column slab -> L2-resident after first row.
__global__ __launch_bounds__(256) void fixup_k(const float* __restrict__ x, const float* __restrict__ w_in,
    const float* __restrict__ proj, const float* __restrict__ ct, const float* __restrict__ st,
    const int* __restrict__ wl4, const int* __restrict__ cnt4,
    int* __restrict__ hq, int* __restrict__ hk){
  const int bucket = blockIdx.x;
  const int n = cnt4[bucket];
  const int lane = threadIdx.x & 63, wave = threadIdx.x >> 6;
  for (int e = wave; e < n; e += 4){
    int entry = wl4[bucket*BCAP3 + e];
    int s = entry & 8191;
    int tagbh = entry >> 13;
    int tag = tagbh & 1, bh = tagbh >> 1;
    int b = bh >> 4, h = bh & 15;
    const float* xr = x + ((size_t)b*SEQ + s)*KDIM;
    const int c0i = tag*2048 + h*128 + lane;
    // 4 interleaved f64 chains (order change only; error ~1e-12 << 1.6e-5 margin)
    double a0c[4] = {0,0,0,0}, a1c[4] = {0,0,0,0};
    for (int j = 0; j < KDIM; j += 4){
      #pragma unroll
      for (int u2 = 0; u2 < 4; ++u2){
        double xv = (double)xr[j + u2];
        a0c[u2] += xv * (double)w_in[(size_t)(j + u2)*6144 + c0i];
        a1c[u2] += xv * (double)w_in[(size_t)(j + u2)*6144 + c0i + 64];
      }
    }
    double a0 = (a0c[0] + a0c[1]) + (a0c[2] + a0c[3]);
    double a1 = (a1c[0] + a1c[1]) + (a1c[2] + a1c[3]);
    double c = (double)ct[(size_t)s*64 + lane];
    double sn = (double)st[(size_t)s*64 + lane];
    double r0 = a0*c - a1*sn;
    double r1 = a1*c + a0*sn;
    int hs = 0;
    #pragma unroll
    for (int p = 0; p < 7; ++p){
      double part = r0 * (double)proj[lane*7+p] + r1 * (double)proj[(lane+64)*7+p];
      #pragma unroll
      for (int off = 32; off >= 1; off >>= 1) part += __shfl_xor(part, off);
      if (part > 0.0) hs |= (1<<p);
    }
    if (lane == 0) (tag ? hk : hq)[bh*SEQ + s] = hs;
  }
}

// ---------- stable counting sort by hash (128 bins), chunked-parallel ----------
__global__ __launch_bounds__(256) void sort_k(const int* __restrict__ hsh, int* __restrict__ idx){
  const int bh = blockIdx.x, tid = threadIdx.x;
  __shared__ unsigned char hl[SEQ];
  __shared__ unsigned short hist[128*256];
  __shared__ unsigned int part[256];
  const int* hrow = hsh + bh*SEQ;
  for (int i = tid; i < SEQ; i += 256) hl[i] = (unsigned char)hrow[i];
  u32* h32 = (u32*)hist;
  for (int i = tid; i < 128*256/2; i += 256) h32[i] = 0;
  __syncthreads();
  #pragma unroll 1
  for (int j = 0; j < 32; ++j){
    int hv = hl[tid*32 + j];
    hist[hv*256 + tid] = (unsigned short)(hist[hv*256 + tid] + 1);
  }
  __syncthreads();
  unsigned int s = 0;
  #pragma unroll 1
  for (int f = tid*128; f < tid*128 + 128; ++f) s += hist[f];
  part[tid] = s;
  __syncthreads();
  for (int off = 1; off < 256; off <<= 1){
    unsigned int v = (tid >= off) ? part[tid - off] : 0u;
    __syncthreads();
    part[tid] += v;
    __syncthreads();
  }
  unsigned int run = (tid == 0) ? 0u : part[tid - 1];
  #pragma unroll 1
  for (int f = tid*128; f < tid*128 + 128; ++f){
    unsigned short c = hist[f];
    hist[f] = (unsigned short)run;
    run += c;
  }
  __syncthreads();
  int* orow = idx + bh*SEQ;
  #pragma unroll 1
  for (int j = 0; j < 32; ++j){
    int i = tid*32 + j;
    int hv = hl[i];
    unsigned short p = hist[hv*256 + tid];
    hist[hv*256 + tid] = (unsigned short)(p + 1);
    orow[p] = i;
  }
}

// ---------- fused block + sampled attention: 512-thread blocks (128 q-rows) ----------
__global__ __launch_bounds__(512) void attn_k(const f16* __restrict__ qr, const f16* __restrict__ kr,
    const f16* __restrict__ v, const int* __restrict__ qidx, const int* __restrict__ kidx,
    const int* __restrict__ smp, f16* __restrict__ out){
  const int tid = threadIdx.x, lane = tid & 63, wave = tid >> 6;
  const int blk = blockIdx.x, bh = blockIdx.y;
  const int b = bh >> 4, h = bh & 15;
  const int qblock = blk >> 1;
  __shared__ f16 Kl[32*136];
  __shared__ f16 Vt[128*40];
  __shared__ float biasl[256];
  __shared__ int kid[512];
  const int g = lane >> 4, q_ = lane & 15;
  {
    int j = tid;
    int kpos;
    if (j < 256) kpos = qblock*256 + j;
    else {
      kpos = smp[bh*256 + (j-256)];
      biasl[j-256] = ((kpos >> 8) == qblock) ? -1e30f : LOGW;
    }
    kid[j] = kidx[bh*SEQ + kpos];
  }
  const int qpos = blk*128 + wave*16 + q_;
  const int qi = qidx[bh*SEQ + qpos];
  const f16* qb = qr + ((size_t)bh*SEQ + qi)*HDIM;
  f16x8 qf[4];
  #pragma unroll
  for (int c=0;c<4;c++) qf[c] = *(const f16x8*)(qb + c*32 + g*8);
  f32x4 O[8];
  #pragma unroll
  for (int c=0;c<8;c++) O[c] = (f32x4){0.f,0.f,0.f,0.f};
  float m_run = -1e30f, l_run = 0.f;
  __syncthreads();
  const int kkK = tid >> 3, segK = tid & 7;
  const int kk2 = tid & 15, d0 = (tid >> 4) * 8;
  f16x8 pk0, pk1, pv0, pv1;
  if (tid < 256){
    int krw = kid[kkK];
    const f16* ks = kr + ((size_t)bh*SEQ + krw)*HDIM + segK*16;
    pk0 = *(const f16x8*)ks; pk1 = *(const f16x8*)(ks + 8);
    int r0 = kid[2*kk2], r1 = kid[2*kk2 + 1];
    pv0 = *(const f16x8*)(v + ((size_t)bh*SEQ + r0)*HDIM + d0);
    pv1 = *(const f16x8*)(v + ((size_t)bh*SEQ + r1)*HDIM + d0);
  }
  for (int t = 0; t < 16; ++t){
    if (tid < 256){
      *(f16x8*)&Kl[kkK*136 + segK*16]     = pk0;
      *(f16x8*)&Kl[kkK*136 + segK*16 + 8] = pk1;
      #pragma unroll
      for (int i=0;i<8;i++){
        union { f16 h[2]; u32 u; } pr;
        pr.h[0] = pv0[i]; pr.h[1] = pv1[i];
        *(u32*)&Vt[(d0+i)*40 + 2*kk2] = pr.u;
      }
    }
    __syncthreads();
    if (t < 15 && tid < 256){
      int jb = (t+1)*32;
      int krw = kid[jb + kkK];
      const f16* ks = kr + ((size_t)bh*SEQ + krw)*HDIM + segK*16;
      pk0 = *(const f16x8*)ks; pk1 = *(const f16x8*)(ks + 8);
      int r0 = kid[jb + 2*kk2], r1 = kid[jb + 2*kk2 + 1];
      pv0 = *(const f16x8*)(v + ((size_t)bh*SEQ + r0)*HDIM + d0);
      pv1 = *(const f16x8*)(v + ((size_t)bh*SEQ + r1)*HDIM + d0);
    }
    f32x4 c0 = (f32x4){0.f,0.f,0.f,0.f}, c1 = (f32x4){0.f,0.f,0.f,0.f};
    #pragma unroll
    for (int c=0;c<4;c++){
      f16x8 k0 = *(const f16x8*)&Kl[q_*136 + c*32 + g*8];
      f16x8 k1 = *(const f16x8*)&Kl[(16+q_)*136 + c*32 + g*8];
      c0 = mfma16(k0, qf[c], c0);
      c1 = mfma16(k1, qf[c], c1);
    }
    float sc[8];
    if (t < 8){
      #pragma unroll
      for (int j=0;j<4;j++){ sc[j] = c0[j]*SCALE; sc[4+j] = c1[j]*SCALE; }
    } else {
      const float* bb = &biasl[(t-8)*32];
      #pragma unroll
      for (int j=0;j<4;j++){ sc[j] = c0[j]*SCALE + bb[g*4+j]; sc[4+j] = c1[j]*SCALE + bb[16+g*4+j]; }
    }
    float mx = sc[0];
    #pragma unroll
    for (int i=1;i<8;i++) mx = fmaxf(mx, sc[i]);
    mx = fmaxf(mx, __shfl_xor(mx, 16));
    mx = fmaxf(mx, __shfl_xor(mx, 32));
    float mnew = fmaxf(m_run, mx);
    float al = __expf(m_run - mnew);
    float p[8]; float ps = 0.f;
    #pragma unroll
    for (int i=0;i<8;i++){ p[i] = __expf(sc[i] - mnew); ps += p[i]; }
    ps += __shfl_xor(ps, 16);
    ps += __shfl_xor(ps, 32);
    l_run = l_run * al + ps;
    m_run = mnew;
    float aj0 = __shfl(al, g*4+0), aj1 = __shfl(al, g*4+1);
    float aj2 = __shfl(al, g*4+2), aj3 = __shfl(al, g*4+3);
    #pragma unroll
    for (int c=0;c<8;c++){ O[c][0]*=aj0; O[c][1]*=aj1; O[c][2]*=aj2; O[c][3]*=aj3; }
    union { f16 h[2]; u32 u; } pk;
    pk.h[0]=(f16)p[0]; pk.h[1]=(f16)p[1]; u32 A0 = pk.u;
    pk.h[0]=(f16)p[2]; pk.h[1]=(f16)p[3]; u32 A1 = pk.u;
    pk.h[0]=(f16)p[4]; pk.h[1]=(f16)p[5]; u32 B0 = pk.u;
    pk.h[0]=(f16)p[6]; pk.h[1]=(f16)p[7]; u32 B1 = pk.u;
    int srcA = (((2*g)&3)<<4) | q_;
    int srcB = ((((2*g)+1)&3)<<4) | q_;
    bool selh = g >= 2;
    u32 xa0 = __shfl(A0, srcA), xb0 = __shfl(B0, srcA);
    u32 xa1 = __shfl(A1, srcA), xb1 = __shfl(B1, srcA);
    u32 xa2 = __shfl(A0, srcB), xb2 = __shfl(B0, srcB);
    u32 xa3 = __shfl(A1, srcB), xb3 = __shfl(B1, srcB);
    union { u32 w[4]; f16x8 f; } pf;
    pf.w[0] = selh ? xb0 : xa0;
    pf.w[1] = selh ? xb1 : xa1;
    pf.w[2] = selh ? xb2 : xa2;
    pf.w[3] = selh ? xb3 : xa3;
    #pragma unroll
    for (int c=0;c<8;c++){
      f16x8 vf = *(const f16x8*)&Vt[(c*16 + q_)*40 + g*8];
      O[c] = mfma16(pf.f, vf, O[c]);
    }
    __syncthreads();
  }
  float li0 = 1.f/__shfl(l_run, g*4+0), li1 = 1.f/__shfl(l_run, g*4+1);
  float li2 = 1.f/__shfl(l_run, g*4+2), li3 = 1.f/__shfl(l_run, g*4+3);
  const int posbase = blk*128 + wave*16;
  #pragma unroll
  for (int j=0;j<4;j++){
    float li = (j==0)?li0:((j==1)?li1:((j==2)?li2:li3));
    int sorig = qidx[bh*SEQ + posbase + g*4 + j];
    f16* dst = out + (((size_t)b*SEQ + sorig)*NH + h)*HDIM;
    #pragma unroll
    for (int c=0;c<8;c++) dst[c*16 + q_] = (f16)(O[c][j] * li);
  }
}

extern "C" void kernel_launch(void* const* d_in, const int* in_sizes, int n_in,
                              void* d_out, int out_size, void* d_ws, size_t ws_size,
                              hipStream_t stream) {
  (void)in_sizes; (void)n_in; (void)out_size; (void)ws_size;
  const float* x     = (const float*)d_in[0];
  const float* w_in  = (const float*)d_in[1];
  const float* w_out = (const float*)d_in[2];
  const float* proj  = (const float*)d_in[3];
  const int*   smp   = (const int*)d_in[4];
  float* out = (float*)d_out;

  char* ws = (char*)d_ws;
  size_t off = 0;
  auto alloc = [&](size_t bytes){ void* p = ws + off; off += (bytes + 255) & ~(size_t)255; return p; };
  f16*   xh   = (f16*)alloc((size_t)16384*2048*2);
  f16*   wh   = (f16*)alloc((size_t)6144*2048*2);
  f16*   wl   = (f16*)alloc((size_t)4096*2048*2);
  f16*   wo   = (f16*)alloc((size_t)2048*2048*2);
  f16*   qf   = (f16*)alloc((size_t)BHCNT*SEQ*HDIM*2);
  f16*   kf   = (f16*)alloc((size_t)BHCNT*SEQ*HDIM*2);
  f16*   vv   = (f16*)alloc((size_t)BHCNT*SEQ*HDIM*2);
  f16*   attn = (f16*)alloc((size_t)BHCNT*SEQ*HDIM*2);
  float* cost = (float*)alloc((size_t)SEQ*64*4);
  float* sint = (float*)alloc((size_t)SEQ*64*4);
  int*   hq   = (int*)alloc((size_t)BHCNT*SEQ*4);
  int*   hk   = (int*)alloc((size_t)BHCNT*SEQ*4);
  int*   qidx = (int*)alloc((size_t)BHCNT*SEQ*4);
  int*   kidx = (int*)alloc((size_t)BHCNT*SEQ*4);
  int*   wlst = (int*)alloc((size_t)MAXWL*2*4);
  int*   wlst2= (int*)alloc((size_t)32*BCAP*4);
  int*   wlst3= (int*)alloc((size_t)MAXWL*2*4);
  int*   wlst4= (int*)alloc((size_t)32*BCAP3*4);
  int*   cnt2 = (int*)alloc(256);
  int*   cnt4 = (int*)alloc(256);
  int*   flags= (int*)alloc(256);

  int* wcnt  = flags;
  int* wcnt3 = flags + 1;

  zero_k<<<1, 1, 0, stream>>>(flags);
  split_x_k<<<32768, 256, 0, stream>>>(x, xh);
  transpose_k<<<dim3(192,64), dim3(32,8), 0, stream>>>(w_in, wh, wl, 2048, 6144, 4096);
  transpose_k<<<dim3(64,64),  dim3(32,8), 0, stream>>>(w_out, wo, nullptr, 2048, 2048, 0);
  rope_table_k<<<2048, 256, 0, stream>>>(cost, sint);

  // fused q/k/v GEMM: L2-blocked traversal
  gemm_k<1,48,6><<<6144, 256, 0, stream>>>(xh, wh, qf, kf, vv, nullptr, 0);

  rope_hash_k<<<dim3(2048,32), 256, 0, stream>>>(qf, cost, sint, proj, hq, 0, wlst, wcnt);
  rope_hash_k<<<dim3(2048,32), 256, 0, stream>>>(kf, cost, sint, proj, hk, 1, wlst, wcnt);

  // tier-2: bucket -> fused gathered split-grade GEMM + rehash
  bucket_k<BCAP><<<32, 256, 0, stream>>>(wlst, wcnt, wlst2, cnt2, flags);
  t2_k<<<dim3(16,32), 256, 0, stream>>>(x, wh, wl, wlst2, cnt2, cost, sint, proj,
                                        hq, hk, wlst3, wcnt3);
  // tier-3: bucket wl3, then exact-f64 with per-bucket L2 slab reuse
  bucket_k<BCAP3><<<32, 256, 0, stream>>>(wlst3, wcnt3, wlst4, cnt4, flags);
  fixup_k<<<32, 256, 0, stream>>>(x, w_in, proj, cost, sint, wlst4, cnt4, hq, hk);

  sort_k<<<32, 256, 0, stream>>>(hq, qidx);
  sort_k<<<32, 256, 0, stream>>>(hk, kidx);

  attn_k<<<dim3(64,32), 512, 0, stream>>>(qf, kf, vv, qidx, kidx, smp, attn);

  gemm_k<0,16,8><<<2048, 256, 0, stream>>>(attn, wo, nullptr, nullptr, nullptr, out, 2048);

  diag_k<<<1, 1, 0, stream>>>(flags, out);
}

// Round 18
// 1480.451 us; speedup vs baseline: 2.8054x; 2.8054x over previous
//
#include <hip/hip_runtime.h>
#include <stdint.h>

typedef _Float16 f16;
typedef _Float16 f16x8 __attribute__((ext_vector_type(8)));
typedef float f32x4 __attribute__((ext_vector_type(4)));
typedef uint32_t u32;

#define SEQ 8192
#define NH 16
#define HDIM 128
#define BHCNT 32
#define KDIM 2048
#define SCALE 0.08838834764831845f
#define LOGW 3.4657359027997265f
#define TAU1 0.06f
#define TAU 6e-3f
#define MAXWL 32768
#define BCAP 1024

__device__ __forceinline__ f32x4 mfma16(f16x8 a, f16x8 b, f32x4 c){
  return __builtin_amdgcn_mfma_f32_16x16x32_f16(a, b, c, 0, 0, 0);
}

__device__ __forceinline__ void g2l16(const f16* g, f16* l){
  __builtin_amdgcn_global_load_lds(
      (const __attribute__((address_space(1))) void*)g,
      (__attribute__((address_space(3))) void*)l, 16, 0, 0);
}

// ---------- prep: x -> f16 ----------
__global__ __launch_bounds__(256) void split_x_k(const float* __restrict__ x,
                                                 f16* __restrict__ xh){
  size_t i = ((size_t)blockIdx.x * 256 + threadIdx.x) * 4;
  float4 v = *(const float4*)(x + i);
  union { f16 h[4]; ushort4 u; } a;
  a.h[0]=(f16)v.x; a.h[1]=(f16)v.y; a.h[2]=(f16)v.z; a.h[3]=(f16)v.w;
  *(ushort4*)(xh + i) = a.u;
}

// ---------- prep: transpose+convert weights (in [Kd][Nd] -> out [Nd][Kd]) ----------
__global__ void transpose_k(const float* __restrict__ in, f16* __restrict__ ohi,
                            f16* __restrict__ olo, int Kd, int Nd, int NLO){
  __shared__ float t[32][33];
  int tx = threadIdx.x, ty = threadIdx.y;
  int n0 = blockIdx.x*32, k0 = blockIdx.y*32;
  #pragma unroll
  for (int i=0;i<4;i++) t[ty+i*8][tx] = in[(size_t)(k0+ty+i*8)*Nd + n0+tx];
  __syncthreads();
  #pragma unroll
  for (int i=0;i<4;i++){
    int n = n0 + ty + i*8, k = k0 + tx;
    float v = t[tx][ty+i*8];
    f16 h = (f16)v;
    ohi[(size_t)n*Kd + k] = h;
    if (n < NLO) olo[(size_t)n*Kd + k] = (f16)(v - (float)h);
  }
}

// ---------- prep: rope cos/sin table (numpy-exact inv_freq double rounding) ----------
__global__ __launch_bounds__(256) void rope_table_k(float* __restrict__ ct, float* __restrict__ st){
  int i = blockIdx.x * 256 + threadIdx.x;
  int s = i >> 6, d = i & 63;
  float p32 = (float)pow(10000.0, (double)d / 64.0);
  float inv = __fdiv_rn(1.0f, p32);
  float f = __fmul_rn((float)s, inv);
  double a = (double)f;
  ct[i] = (float)cos(a);
  st[i] = (float)sin(a);
}

__global__ void zero_k(int* p){ p[0] = 0; p[1] = 0; p[2] = 0; }

// ---------- diagnostic: only fires if flagging machinery is broken ----------
__global__ void diag_k(const int* __restrict__ flags, float* __restrict__ out){
  int c = flags[0];
  if (c == 0 || c >= MAXWL || flags[2]) out[0] = 1.0e9f + (float)c;
}

// ---------- GEMM: A[M][K] * Bt[N][K]^T, XCD strip + L2-blocked bcol groups ----------
template<int MODE, int NC, int GS>
__global__ __launch_bounds__(256) void gemm_k(
    const f16* __restrict__ A, const f16* __restrict__ Bt,
    f16* __restrict__ q16, f16* __restrict__ k16, f16* __restrict__ v16,
    float* __restrict__ o0, int N){
  __shared__ f16 sm[8192];
  const int tid = threadIdx.x, lane = tid & 63, wave = tid >> 6;
  const int wr = wave >> 1, wc = wave & 1;
  const int wg = blockIdx.x;
  const int xcd = wg & 7, wgl = wg >> 3;
  const int grp = wgl / (16*GS);
  const int rem = wgl % (16*GS);
  const int brow = xcd*16 + rem / GS;
  const int bcol = grp*GS + rem % GS;
  const int g = lane >> 4, q_ = lane & 15;
  f32x4 acc[4][4];
  #pragma unroll
  for (int m=0;m<4;m++)
    #pragma unroll
    for (int n=0;n<4;n++) acc[m][n] = (f32x4){0.f,0.f,0.f,0.f};
  const int srow = tid >> 2, sseg = tid & 3;
  const int scol = (sseg ^ (srow & 3)) * 8;
  const f16* ga0 = A  + (size_t)(brow*128 + srow)*KDIM + scol;
  const f16* gb0 = Bt + (size_t)(bcol*128 + srow)*KDIM + scol;
  f16* As = sm; f16* Bs = sm + 4096;
  f16* dA0 = As + wave*512; f16* dA1 = As + 2048 + wave*512;
  f16* dB0 = Bs + wave*512; f16* dB1 = Bs + 2048 + wave*512;
  const int aoff = (wr*64 + q_)*32 + (g ^ (q_ & 3))*8;
  const int boff = (wc*64 + q_)*32 + (g ^ (q_ & 3))*8;
  for (int kt = 0; kt < KDIM/32; ++kt){
    const size_t ko = (size_t)kt * 32;
    g2l16(ga0 + ko, dA0); g2l16(ga0 + (size_t)64*KDIM + ko, dA1);
    g2l16(gb0 + ko, dB0); g2l16(gb0 + (size_t)64*KDIM + ko, dB1);
    __syncthreads();
    f16x8 af[4];
    #pragma unroll
    for (int m=0;m<4;m++) af[m] = *(const f16x8*)&As[aoff + m*16*32];
    #pragma unroll
    for (int n=0;n<4;n++){
      f16x8 bf = *(const f16x8*)&Bs[boff + n*16*32];
      #pragma unroll
      for (int m=0;m<4;m++) acc[m][n] = mfma16(af[m], bf, acc[m][n]);
    }
    __syncthreads();
  }
  #pragma unroll
  for (int m=0;m<4;m++)
    #pragma unroll
    for (int n=0;n<4;n++)
      #pragma unroll
      for (int j=0;j<4;j++){
        int row = brow*128 + wr*64 + m*16 + g*4 + j;
        int col = bcol*128 + wc*64 + n*16 + q_;
        float v = acc[m][n][j];
        if constexpr (MODE == 0){
          o0[(size_t)row * N + col] = v;
        } else {
          int b = row >> 13, s = row & 8191;
          int sec = col >> 11;                 // 0=q, 1=k, 2=v
          int cl = col & 2047;
          int h = cl >> 7, hd = cl & 127;
          f16* dst = (sec == 0) ? q16 : ((sec == 1) ? k16 : v16);
          dst[(((size_t)b*NH + h)*SEQ + s)*HDIM + hd] = (f16)v;
        }
      }
}

// ---------- rope (f32 math, f16 in/out in place) + LSH hash + TAU1 flagging ----------
__global__ __launch_bounds__(256) void rope_hash_k(f16* __restrict__ qk, const float* __restrict__ ct,
    const float* __restrict__ st, const float* __restrict__ proj, int* __restrict__ hout,
    int tag, int* __restrict__ wl, int* __restrict__ wcnt){
  const int lane = threadIdx.x & 63, wave = threadIdx.x >> 6;
  const int s = blockIdx.x * 4 + wave, bh = blockIdx.y;
  f16* row = qk + ((size_t)bh * SEQ + s) * HDIM;
  float vx = (float)row[2*lane], vy = (float)row[2*lane+1];
  float ox = __shfl_xor(vx, 32), oy = __shfl_xor(vy, 32);
  const int dl = 2*lane, di = dl & 63;
  const float* cb = ct + (size_t)s*64; const float* sb = st + (size_t)s*64;
  float c0 = cb[di], c1 = cb[di+1], sn0 = sb[di], sn1 = sb[di+1];
  float r0, r1;
  if (lane < 32){ r0 = vx*c0 - ox*sn0; r1 = vy*c1 - oy*sn1; }
  else          { r0 = vx*c0 + ox*sn0; r1 = vy*c1 + oy*sn1; }
  union { f16 h[2]; u32 u; } pk;
  pk.h[0] = (f16)r0; pk.h[1] = (f16)r1;
  *(u32*)(row + dl) = pk.u;
  float part[7];
  #pragma unroll
  for (int p=0;p<7;p++) part[p] = r0*proj[dl*7+p] + r1*proj[(dl+1)*7+p];
  #pragma unroll
  for (int off=32; off>=1; off>>=1){
    #pragma unroll
    for (int p=0;p<7;p++) part[p] += __shfl_xor(part[p], off);
  }
  if (lane == 0){
    int hs = 0; float mn = 1e30f;
    #pragma unroll
    for (int p=0;p<7;p++){ if (part[p] > 0.f) hs |= (1<<p); mn = fminf(mn, fabsf(part[p])); }
    hout[bh*SEQ + s] = hs;
    if (mn < TAU1){
      int w = atomicAdd(wcnt, 1);
      if (w < MAXWL){ wl[2*w] = (bh<<1) | tag; wl[2*w+1] = s; }
    }
  }
}

// ---------- bucket flagged rows by (tag, head) ----------
template<int CAP>
__global__ __launch_bounds__(256) void bucket_k(const int* __restrict__ wl, const int* __restrict__ wcnt,
    int* __restrict__ wl2, int* __restrict__ cnt2, int* __restrict__ flags){
  const int bucket = blockIdx.x;
  __shared__ int lcnt;
  if (threadIdx.x == 0) lcnt = 0;
  __syncthreads();
  int count = wcnt[0]; if (count > MAXWL) count = MAXWL;
  for (int i = threadIdx.x; i < count; i += 256){
    int tagbh = wl[2*i];
    int tag = tagbh & 1, h = (tagbh >> 1) & 15;
    if (tag*16 + h == bucket){
      int pos = atomicAdd(&lcnt, 1);
      if (pos < CAP) wl2[bucket*CAP + pos] = (tagbh << 13) | wl[2*i+1];
    }
  }
  __syncthreads();
  if (threadIdx.x == 0){
    cnt2[bucket] = (lcnt > CAP) ? CAP : lcnt;
    if (lcnt > CAP) atomicExch(&flags[2], 1);
  }
}

// ---------- tier-2b (FUSED): gathered split-grade GEMM + rope + rehash, 64-row batches ----------
__global__ __launch_bounds__(256) void t2_k(const float* __restrict__ x,
    const f16* __restrict__ wh, const f16* __restrict__ wlo,
    const int* __restrict__ wl2, const int* __restrict__ cnt2,
    const float* __restrict__ ct, const float* __restrict__ st, const float* __restrict__ proj,
    int* __restrict__ hq, int* __restrict__ hk, int* __restrict__ wl3, int* __restrict__ wcnt3){
  const int bucket = blockIdx.y;
  const int nrows = cnt2[bucket];
  const int base = blockIdx.x * 64;
  if (base >= nrows) return;
  const int tid = threadIdx.x, lane = tid & 63, wave = tid >> 6;
  const int g = lane >> 4, q_ = lane & 15;
  __shared__ f16 Ah[64*32], Alo[64*32], Bh[128*32], Bl[128*32];
  __shared__ float S[64][128];
  __shared__ int rs[64], ent[64];
  if (tid < 64){
    int idx = base + tid;
    int e = wl2[bucket*BCAP + (idx < nrows ? idx : 0)];
    ent[tid] = e;
    int s = e & 8191;
    int b = e >> 18;
    rs[tid] = b * SEQ + s;
  }
  __syncthreads();
  const int tag = bucket >> 4, h = bucket & 15;
  const f16* Wh = wh  + ((size_t)(tag*2048 + h*128)) * KDIM;
  const f16* Wl = wlo + ((size_t)(tag*2048 + h*128)) * KDIM;
  f32x4 acc[8];
  #pragma unroll
  for (int n=0;n<8;n++) acc[n] = (f32x4){0.f,0.f,0.f,0.f};
  const int arow = tid >> 2, aseg = tid & 3;
  const int bcol = tid >> 1, bhalf = tid & 1;
  const size_t abase = (size_t)rs[arow]*KDIM + aseg*8;
  const size_t bbase = (size_t)bcol*KDIM + bhalf*16;
  for (int kt = 0; kt < 64; ++kt){
    const int k0 = kt*32;
    {
      union { float4 f4[2]; float f[8]; } xa;
      xa.f4[0] = *(const float4*)(x + abase + k0);
      xa.f4[1] = *(const float4*)(x + abase + k0 + 4);
      union { f16 h[8]; f16x8 v; } hh, ll;
      #pragma unroll
      for (int i=0;i<8;i++){
        f16 hv = (f16)xa.f[i];
        hh.h[i] = hv;
        ll.h[i] = (f16)(xa.f[i] - (float)hv);
      }
      *(f16x8*)&Ah [arow*32 + aseg*8] = hh.v;
      *(f16x8*)&Alo[arow*32 + aseg*8] = ll.v;
    }
    *(f16x8*)&Bh[bcol*32 + bhalf*16]     = *(const f16x8*)(Wh + bbase + k0);
    *(f16x8*)&Bh[bcol*32 + bhalf*16 + 8] = *(const f16x8*)(Wh + bbase + k0 + 8);
    *(f16x8*)&Bl[bcol*32 + bhalf*16]     = *(const f16x8*)(Wl + bbase + k0);
    *(f16x8*)&Bl[bcol*32 + bhalf*16 + 8] = *(const f16x8*)(Wl + bbase + k0 + 8);
    __syncthreads();
    f16x8 ah = *(const f16x8*)&Ah [(wave*16 + q_)*32 + g*8];
    f16x8 al = *(const f16x8*)&Alo[(wave*16 + q_)*32 + g*8];
    #pragma unroll
    for (int n=0;n<8;n++){
      f16x8 bh8 = *(const f16x8*)&Bh[(n*16 + q_)*32 + g*8];
      f16x8 bl8 = *(const f16x8*)&Bl[(n*16 + q_)*32 + g*8];
      acc[n] = mfma16(ah, bh8, acc[n]);
      acc[n] = mfma16(ah, bl8, acc[n]);
      acc[n] = mfma16(al, bh8, acc[n]);
    }
    __syncthreads();
  }
  #pragma unroll
  for (int n=0;n<8;n++)
    #pragma unroll
    for (int j=0;j<4;j++)
      S[wave*16 + g*4 + j][n*16 + q_] = acc[n][j];
  __syncthreads();
  for (int r = 0; r < 16; ++r){
    int row = wave*16 + r;
    int gidx = base + row;
    if (gidx >= nrows) break;
    int e = ent[row];
    int s = e & 8191;
    int tagbh = e >> 13;
    int bh = tagbh >> 1;
    float vx = S[row][2*lane], vy = S[row][2*lane+1];
    float ox = __shfl_xor(vx, 32), oy = __shfl_xor(vy, 32);
    const int dl = 2*lane, di = dl & 63;
    float c0 = ct[(size_t)s*64 + di], c1v = ct[(size_t)s*64 + di + 1];
    float sn0 = st[(size_t)s*64 + di], sn1 = st[(size_t)s*64 + di + 1];
    float r0, r1;
    if (lane < 32){ r0 = vx*c0 - ox*sn0; r1 = vy*c1v - oy*sn1; }
    else          { r0 = vx*c0 + ox*sn0; r1 = vy*c1v + oy*sn1; }
    float part[7];
    #pragma unroll
    for (int p=0;p<7;p++) part[p] = r0*proj[dl*7+p] + r1*proj[(dl+1)*7+p];
    #pragma unroll
    for (int off=32; off>=1; off>>=1){
      #pragma unroll
      for (int p=0;p<7;p++) part[p] += __shfl_xor(part[p], off);
    }
    if (lane == 0){
      int hs = 0; float mn = 1e30f;
      #pragma unroll
      for (int p=0;p<7;p++){ if (part[p] > 0.f) hs |= (1<<p); mn = fminf(mn, fabsf(part[p])); }
      ((tagbh & 1) ? hk : hq)[bh*SEQ + s] = hs;
      if (mn < TAU){
        int w = atomicAdd(wcnt3, 1);
        if (w < MAXWL){ wl3[2*w] = tagbh; wl3[2*w+1] = s; }
      }
    }
  }
}

// ---------- tier-3: exact-f64 recompute, ONE BLOCK PER ROW, K parallelized 4-way ----------
// 256 threads = 64 columns x 4 K-chunks of 512; per-thread 4-interleaved f64 chains;
// deterministic fixed-order combine via LDS; wave 0 does rope + hash.
__global__ __launch_bounds__(256) void fixup_k(const float* __restrict__ x, const float* __restrict__ w_in,
    const float* __restrict__ proj, const float* __restrict__ ct, const float* __restrict__ st,
    const int* __restrict__ wl, const int* __restrict__ wcnt,
    int* __restrict__ hq, int* __restrict__ hk){
  __shared__ double pa0[4][64], pa1[4][64];
  int count = *wcnt; if (count > MAXWL) count = MAXWL;
  const int tid = threadIdx.x;
  const int col = tid & 63, chunk = tid >> 6;
  for (int e = blockIdx.x; e < count; e += gridDim.x){
    int tagbh = wl[2*e], s = wl[2*e+1];
    int tag = tagbh & 1, bh = tagbh >> 1;
    int b = bh >> 4, h = bh & 15;
    const float* xr = x + ((size_t)b*SEQ + s)*KDIM;
    const int c0i = tag*2048 + h*128 + col;
    double a0c[4] = {0,0,0,0}, a1c[4] = {0,0,0,0};
    const int k0 = chunk*512;
    for (int j = 0; j < 512; j += 4){
      #pragma unroll
      for (int u2 = 0; u2 < 4; ++u2){
        double xv = (double)xr[k0 + j + u2];
        a0c[u2] += xv * (double)w_in[(size_t)(k0 + j + u2)*6144 + c0i];
        a1c[u2] += xv * (double)w_in[(size_t)(k0 + j + u2)*6144 + c0i + 64];
      }
    }
    pa0[chunk][col] = (a0c[0] + a0c[1]) + (a0c[2] + a0c[3]);
    pa1[chunk][col] = (a1c[0] + a1c[1]) + (a1c[2] + a1c[3]);
    __syncthreads();
    if (tid < 64){
      const int lane = tid;
      double a0 = (pa0[0][lane] + pa0[1][lane]) + (pa0[2][lane] + pa0[3][lane]);
      double a1 = (pa1[0][lane] + pa1[1][lane]) + (pa1[2][lane] + pa1[3][lane]);
      double c = (double)ct[(size_t)s*64 + lane];
      double sn = (double)st[(size_t)s*64 + lane];
      double r0 = a0*c - a1*sn;
      double r1 = a1*c + a0*sn;
      int hs = 0;
      #pragma unroll
      for (int p = 0; p < 7; ++p){
        double part = r0 * (double)proj[lane*7+p] + r1 * (double)proj[(lane+64)*7+p];
        #pragma unroll
        for (int off = 32; off >= 1; off >>= 1) part += __shfl_xor(part, off);
        if (part > 0.0) hs |= (1<<p);
      }
      if (lane == 0) (tag ? hk : hq)[bh*SEQ + s] = hs;
    }
    __syncthreads();
  }
}

// ---------- stable counting sort by hash (128 bins), chunked-parallel ----------
__global__ __launch_bounds__(256) void sort_k(const int* __restrict__ hsh, int* __restrict__ idx){
  const int bh = blockIdx.x, tid = threadIdx.x;
  __shared__ unsigned char hl[SEQ];
  __shared__ unsigned short hist[128*256];
  __shared__ unsigned int part[256];
  const int* hrow = hsh + bh*SEQ;
  for (int i = tid; i < SEQ; i += 256) hl[i] = (unsigned char)hrow[i];
  u32* h32 = (u32*)hist;
  for (int i = tid; i < 128*256/2; i += 256) h32[i] = 0;
  __syncthreads();
  #pragma unroll 1
  for (int j = 0; j < 32; ++j){
    int hv = hl[tid*32 + j];
    hist[hv*256 + tid] = (unsigned short)(hist[hv*256 + tid] + 1);
  }
  __syncthreads();
  unsigned int s = 0;
  #pragma unroll 1
  for (int f = tid*128; f < tid*128 + 128; ++f) s += hist[f];
  part[tid] = s;
  __syncthreads();
  for (int off = 1; off < 256; off <<= 1){
    unsigned int v = (tid >= off) ? part[tid - off] : 0u;
    __syncthreads();
    part[tid] += v;
    __syncthreads();
  }
  unsigned int run = (tid == 0) ? 0u : part[tid - 1];
  #pragma unroll 1
  for (int f = tid*128; f < tid*128 + 128; ++f){
    unsigned short c = hist[f];
    hist[f] = (unsigned short)run;
    run += c;
  }
  __syncthreads();
  int* orow = idx + bh*SEQ;
  #pragma unroll 1
  for (int j = 0; j < 32; ++j){
    int i = tid*32 + j;
    int hv = hl[i];
    unsigned short p = hist[hv*256 + tid];
    hist[hv*256 + tid] = (unsigned short)(p + 1);
    orow[p] = i;
  }
}

// ---------- fused block + sampled attention: 512-thread blocks (128 q-rows) ----------
__global__ __launch_bounds__(512) void attn_k(const f16* __restrict__ qr, const f16* __restrict__ kr,
    const f16* __restrict__ v, const int* __restrict__ qidx, const int* __restrict__ kidx,
    const int* __restrict__ smp, f16* __restrict__ out){
  const int tid = threadIdx.x, lane = tid & 63, wave = tid >> 6;
  const int blk = blockIdx.x, bh = blockIdx.y;
  const int b = bh >> 4, h = bh & 15;
  const int qblock = blk >> 1;
  __shared__ f16 Kl[32*136];
  __shared__ f16 Vt[128*40];
  __shared__ float biasl[256];
  __shared__ int kid[512];
  const int g = lane >> 4, q_ = lane & 15;
  {
    int j = tid;
    int kpos;
    if (j < 256) kpos = qblock*256 + j;
    else {
      kpos = smp[bh*256 + (j-256)];
      biasl[j-256] = ((kpos >> 8) == qblock) ? -1e30f : LOGW;
    }
    kid[j] = kidx[bh*SEQ + kpos];
  }
  const int qpos = blk*128 + wave*16 + q_;
  const int qi = qidx[bh*SEQ + qpos];
  const f16* qb = qr + ((size_t)bh*SEQ + qi)*HDIM;
  f16x8 qf[4];
  #pragma unroll
  for (int c=0;c<4;c++) qf[c] = *(const f16x8*)(qb + c*32 + g*8);
  f32x4 O[8];
  #pragma unroll
  for (int c=0;c<8;c++) O[c] = (f32x4){0.f,0.f,0.f,0.f};
  float m_run = -1e30f, l_run = 0.f;
  __syncthreads();
  const int kkK = tid >> 3, segK = tid & 7;
  const int kk2 = tid & 15, d0 = (tid >> 4) * 8;
  f16x8 pk0, pk1, pv0, pv1;
  if (tid < 256){
    int krw = kid[kkK];
    const f16* ks = kr + ((size_t)bh*SEQ + krw)*HDIM + segK*16;
    pk0 = *(const f16x8*)ks; pk1 = *(const f16x8*)(ks + 8);
    int r0 = kid[2*kk2], r1 = kid[2*kk2 + 1];
    pv0 = *(const f16x8*)(v + ((size_t)bh*SEQ + r0)*HDIM + d0);
    pv1 = *(const f16x8*)(v + ((size_t)bh*SEQ + r1)*HDIM + d0);
  }
  for (int t = 0; t < 16; ++t){
    if (tid < 256){
      *(f16x8*)&Kl[kkK*136 + segK*16]     = pk0;
      *(f16x8*)&Kl[kkK*136 + segK*16 + 8] = pk1;
      #pragma unroll
      for (int i=0;i<8;i++){
        union { f16 h[2]; u32 u; } pr;
        pr.h[0] = pv0[i]; pr.h[1] = pv1[i];
        *(u32*)&Vt[(d0+i)*40 + 2*kk2] = pr.u;
      }
    }
    __syncthreads();
    if (t < 15 && tid < 256){
      int jb = (t+1)*32;
      int krw = kid[jb + kkK];
      const f16* ks = kr + ((size_t)bh*SEQ + krw)*HDIM + segK*16;
      pk0 = *(const f16x8*)ks; pk1 = *(const f16x8*)(ks + 8);
      int r0 = kid[jb + 2*kk2], r1 = kid[jb + 2*kk2 + 1];
      pv0 = *(const f16x8*)(v + ((size_t)bh*SEQ + r0)*HDIM + d0);
      pv1 = *(const f16x8*)(v + ((size_t)bh*SEQ + r1)*HDIM + d0);
    }
    f32x4 c0 = (f32x4){0.f,0.f,0.f,0.f}, c1 = (f32x4){0.f,0.f,0.f,0.f};
    #pragma unroll
    for (int c=0;c<4;c++){
      f16x8 k0 = *(const f16x8*)&Kl[q_*136 + c*32 + g*8];
      f16x8 k1 = *(const f16x8*)&Kl[(16+q_)*136 + c*32 + g*8];
      c0 = mfma16(k0, qf[c], c0);
      c1 = mfma16(k1, qf[c], c1);
    }
    float sc[8];
    if (t < 8){
      #pragma unroll
      for (int j=0;j<4;j++){ sc[j] = c0[j]*SCALE; sc[4+j] = c1[j]*SCALE; }
    } else {
      const float* bb = &biasl[(t-8)*32];
      #pragma unroll
      for (int j=0;j<4;j++){ sc[j] = c0[j]*SCALE + bb[g*4+j]; sc[4+j] = c1[j]*SCALE + bb[16+g*4+j]; }
    }
    float mx = sc[0];
    #pragma unroll
    for (int i=1;i<8;i++) mx = fmaxf(mx, sc[i]);
    mx = fmaxf(mx, __shfl_xor(mx, 16));
    mx = fmaxf(mx, __shfl_xor(mx, 32));
    float mnew = fmaxf(m_run, mx);
    float al = __expf(m_run - mnew);
    float p[8]; float ps = 0.f;
    #pragma unroll
    for (int i=0;i<8;i++){ p[i] = __expf(sc[i] - mnew); ps += p[i]; }
    ps += __shfl_xor(ps, 16);
    ps += __shfl_xor(ps, 32);
    l_run = l_run * al + ps;
    m_run = mnew;
    float aj0 = __shfl(al, g*4+0), aj1 = __shfl(al, g*4+1);
    float aj2 = __shfl(al, g*4+2), aj3 = __shfl(al, g*4+3);
    #pragma unroll
    for (int c=0;c<8;c++){ O[c][0]*=aj0; O[c][1]*=aj1; O[c][2]*=aj2; O[c][3]*=aj3; }
    union { f16 h[2]; u32 u; } pk;
    pk.h[0]=(f16)p[0]; pk.h[1]=(f16)p[1]; u32 A0 = pk.u;
    pk.h[0]=(f16)p[2]; pk.h[1]=(f16)p[3]; u32 A1 = pk.u;
    pk.h[0]=(f16)p[4]; pk.h[1]=(f16)p[5]; u32 B0 = pk.u;
    pk.h[0]=(f16)p[6]; pk.h[1]=(f16)p[7]; u32 B1 = pk.u;
    int srcA = (((2*g)&3)<<4) | q_;
    int srcB = ((((2*g)+1)&3)<<4) | q_;
    bool selh = g >= 2;
    u32 xa0 = __shfl(A0, srcA), xb0 = __shfl(B0, srcA);
    u32 xa1 = __shfl(A1, srcA), xb1 = __shfl(B1, srcA);
    u32 xa2 = __shfl(A0, srcB), xb2 = __shfl(B0, srcB);
    u32 xa3 = __shfl(A1, srcB), xb3 = __shfl(B1, srcB);
    union { u32 w[4]; f16x8 f; } pf;
    pf.w[0] = selh ? xb0 : xa0;
    pf.w[1] = selh ? xb1 : xa1;
    pf.w[2] = selh ? xb2 : xa2;
    pf.w[3] = selh ? xb3 : xa3;
    #pragma unroll
    for (int c=0;c<8;c++){
      f16x8 vf = *(const f16x8*)&Vt[(c*16 + q_)*40 + g*8];
      O[c] = mfma16(pf.f, vf, O[c]);
    }
    __syncthreads();
  }
  float li0 = 1.f/__shfl(l_run, g*4+0), li1 = 1.f/__shfl(l_run, g*4+1);
  float li2 = 1.f/__shfl(l_run, g*4+2), li3 = 1.f/__shfl(l_run, g*4+3);
  const int posbase = blk*128 + wave*16;
  #pragma unroll
  for (int j=0;j<4;j++){
    float li = (j==0)?li0:((j==1)?li1:((j==2)?li2:li3));
    int sorig = qidx[bh*SEQ + posbase + g*4 + j];
    f16* dst = out + (((size_t)b*SEQ + sorig)*NH + h)*HDIM;
    #pragma unroll
    for (int c=0;c<8;c++) dst[c*16 + q_] = (f16)(O[c][j] * li);
  }
}

extern "C" void kernel_launch(void* const* d_in, const int* in_sizes, int n_in,
                              void* d_out, int out_size, void* d_ws, size_t ws_size,
                              hipStream_t stream) {
  (void)in_sizes; (void)n_in; (void)out_size; (void)ws_size;
  const float* x     = (const float*)d_in[0];
  const float* w_in  = (const float*)d_in[1];
  const float* w_out = (const float*)d_in[2];
  const float* proj  = (const float*)d_in[3];
  const int*   smp   = (const int*)d_in[4];
  float* out = (float*)d_out;

  char* ws = (char*)d_ws;
  size_t off = 0;
  auto alloc = [&](size_t bytes){ void* p = ws + off; off += (bytes + 255) & ~(size_t)255; return p; };
  f16*   xh   = (f16*)alloc((size_t)16384*2048*2);
  f16*   wh   = (f16*)alloc((size_t)6144*2048*2);
  f16*   wl   = (f16*)alloc((size_t)4096*2048*2);
  f16*   wo   = (f16*)alloc((size_t)2048*2048*2);
  f16*   qf   = (f16*)alloc((size_t)BHCNT*SEQ*HDIM*2);
  f16*   kf   = (f16*)alloc((size_t)BHCNT*SEQ*HDIM*2);
  f16*   vv   = (f16*)alloc((size_t)BHCNT*SEQ*HDIM*2);
  f16*   attn = (f16*)alloc((size_t)BHCNT*SEQ*HDIM*2);
  float* cost = (float*)alloc((size_t)SEQ*64*4);
  float* sint = (float*)alloc((size_t)SEQ*64*4);
  int*   hq   = (int*)alloc((size_t)BHCNT*SEQ*4);
  int*   hk   = (int*)alloc((size_t)BHCNT*SEQ*4);
  int*   qidx = (int*)alloc((size_t)BHCNT*SEQ*4);
  int*   kidx = (int*)alloc((size_t)BHCNT*SEQ*4);
  int*   wlst = (int*)alloc((size_t)MAXWL*2*4);
  int*   wlst2= (int*)alloc((size_t)32*BCAP*4);
  int*   wlst3= (int*)alloc((size_t)MAXWL*2*4);
  int*   cnt2 = (int*)alloc(256);
  int*   flags= (int*)alloc(256);

  int* wcnt  = flags;
  int* wcnt3 = flags + 1;

  zero_k<<<1, 1, 0, stream>>>(flags);
  split_x_k<<<32768, 256, 0, stream>>>(x, xh);
  transpose_k<<<dim3(192,64), dim3(32,8), 0, stream>>>(w_in, wh, wl, 2048, 6144, 4096);
  transpose_k<<<dim3(64,64),  dim3(32,8), 0, stream>>>(w_out, wo, nullptr, 2048, 2048, 0);
  rope_table_k<<<2048, 256, 0, stream>>>(cost, sint);

  // fused q/k/v GEMM: L2-blocked traversal
  gemm_k<1,48,6><<<6144, 256, 0, stream>>>(xh, wh, qf, kf, vv, nullptr, 0);

  rope_hash_k<<<dim3(2048,32), 256, 0, stream>>>(qf, cost, sint, proj, hq, 0, wlst, wcnt);
  rope_hash_k<<<dim3(2048,32), 256, 0, stream>>>(kf, cost, sint, proj, hk, 1, wlst, wcnt);

  // tier-2: bucket -> fused gathered split-grade GEMM + rehash
  bucket_k<BCAP><<<32, 256, 0, stream>>>(wlst, wcnt, wlst2, cnt2, flags);
  t2_k<<<dim3(16,32), 256, 0, stream>>>(x, wh, wl, wlst2, cnt2, cost, sint, proj,
                                        hq, hk, wlst3, wcnt3);
  // tier-3: exact f64, one block per flagged row, K parallelized 4-way
  fixup_k<<<1024, 256, 0, stream>>>(x, w_in, proj, cost, sint, wlst3, wcnt3, hq, hk);

  sort_k<<<32, 256, 0, stream>>>(hq, qidx);
  sort_k<<<32, 256, 0, stream>>>(hk, kidx);

  attn_k<<<dim3(64,32), 512, 0, stream>>>(qf, kf, vv, qidx, kidx, smp, attn);

  gemm_k<0,16,8><<<2048, 256, 0, stream>>>(attn, wo, nullptr, nullptr, nullptr, out, 2048);

  diag_k<<<1, 1, 0, stream>>>(flags, out);
}